// Round 3
// baseline (443.675 us; speedup 1.0000x reference)
//
#include <hip/hip_runtime.h>
#include <hip/hip_bf16.h>
#include <stdint.h>

// GCN: out = D^-1/2 A D^-1/2 X W + b
// B=4, N=4096, F_IN=F_OUT=128, all fp32 I/O.
// v5: B (xst) is L2-resident (1 MiB/batch, XCD-swizzled) -> read MFMA B
// fragments DIRECTLY from global with 1-iter register prefetch; no LDS
// staging for B. LDS ops per wave-iter: 13 -> 5 (1 A-write + 4 A-reads).
// A path reverts to v2's 1-deep register prefetch + LDS dbuf + single
// barrier per iter (v4's 2-deep regressed). GEMM A-BW floor = 256 MiB
// ~= 41 us; goal is to push the internal (LDS-pipe) limit below that.

#define NROW 4096
#define FDIM 128
#define NBATCH 4

typedef __bf16 bf16x8 __attribute__((ext_vector_type(8)));
typedef float f32x4 __attribute__((ext_vector_type(4)));

// ---------------- kernel 1: degree + d^{-1/2} ----------------
// one WAVE per row: 64 lanes x 16 float4 = 16 KB row, no LDS, no barrier.
__global__ __launch_bounds__(256) void k_degree(const float* __restrict__ adj,
                                                float* __restrict__ dinv) {
  const int row = blockIdx.x * 4 + (threadIdx.x >> 6);  // b*NROW+n
  const int lane = threadIdx.x & 63;
  const float4* arow = (const float4*)(adj + (size_t)row * NROW);
  float s = 0.f;
#pragma unroll
  for (int i = 0; i < 16; ++i) {
    float4 v = arow[lane + i * 64];
    s += (v.x + v.y) + (v.z + v.w);
  }
#pragma unroll
  for (int off = 32; off > 0; off >>= 1) s += __shfl_down(s, off, 64);
  if (lane == 0) dinv[row] = 1.0f / sqrtf(s + 1e-6f);
}

// ---------------- kernel 2: Xst[b][f][m] = bf16(dinv[b,m] * x[b][m][f]) ----
// blocks 0..511: xst transpose+scale. block 512: wt[o][f] = bf16(W[f][o]).
__global__ __launch_bounds__(256) void k_xst(const float* __restrict__ x,
                                             const float* __restrict__ dinv,
                                             __hip_bfloat16* __restrict__ xst,
                                             const float* __restrict__ w,
                                             __hip_bfloat16* __restrict__ wt) {
  const int bid = blockIdx.x;
  const int tid = threadIdx.x;

  if (bid == 512) {  // W transpose -> bf16 (32 KB, one block)
    const int o = tid >> 1;
    const int f0 = (tid & 1) * 64;
    union { __hip_bfloat16 h[64]; uint4 v[8]; } t;
#pragma unroll
    for (int j = 0; j < 64; ++j)
      t.h[j] = __float2bfloat16(w[(size_t)(f0 + j) * FDIM + o]);
    uint4* dst = (uint4*)(wt + (size_t)o * FDIM + f0);
#pragma unroll
    for (int j = 0; j < 8; ++j) dst[j] = t.v[j];
    return;
  }

  const int b = bid >> 7;            // 0..3
  const int m0 = (bid & 127) * 32;   // 0..4064
  __shared__ float tile[32 * 132];
  {
    const int ml = tid >> 3;          // 0..31
    const int fl = (tid & 7) * 16;    // 0..112
    const float dv = dinv[b * NROW + m0 + ml];
    const float* gx = x + ((size_t)b * NROW + m0 + ml) * FDIM + fl;
    float* dst = &tile[ml * 132 + fl];
#pragma unroll
    for (int j = 0; j < 16; j += 4) {
      float4 v = *(const float4*)(gx + j);
      v.x *= dv; v.y *= dv; v.z *= dv; v.w *= dv;
      *(float4*)(dst + j) = v;
    }
  }
  __syncthreads();
  {
    const int f = tid >> 1;           // 0..127
    const int mc = (tid & 1) * 16;    // 0 or 16
    union { __hip_bfloat16 h[16]; uint4 v[2]; } tmp;
#pragma unroll
    for (int j = 0; j < 16; ++j)
      tmp.h[j] = __float2bfloat16(tile[(mc + j) * 132 + f]);
    __hip_bfloat16* dst = xst + ((size_t)b * FDIM + f) * NROW + m0 + mc;
    *(uint4*)(dst) = tmp.v[0];
    *(uint4*)(dst + 8) = tmp.v[1];
  }
}

// ---------------- kernel 3: main GEMM + fused epilogue ----------------
// 32 rows x 128 cols of Z per block; Kc=64; 4 waves, each 32x32 (2x2 of
// 16x16x32 bf16 MFMA). A: reg prefetch + LDS dbuf, 1 barrier/iter.
// B: direct global (L2) fragment loads, 1-iter register prefetch.
#define MT 32
#define KC 64
#define AS_ST 72    // 64+8 bf16
#define ZS_ST 136   // 128+8

__global__ __launch_bounds__(256, 2)
void k_gemm(const float* __restrict__ adj, const __hip_bfloat16* __restrict__ xst,
            const float* __restrict__ dinv, const __hip_bfloat16* __restrict__ wt,
            const float* __restrict__ bias, float* __restrict__ out) {
  __shared__ union {
    __hip_bfloat16 As[2][MT * AS_ST];   // 9216 B
    __hip_bfloat16 Zs[MT * ZS_ST];      // 8704 B
  } sm;
  __shared__ float dinv_s[MT];

  // XCD swizzle: same batch stays on an XCD pair -> xst slice L2-resident.
  const int bid = blockIdx.x;            // 0..511
  const int xcd = bid & 7;
  const int b = xcd >> 1;                // 0..3
  const int mtile = (bid >> 3) * 2 + (xcd & 1);  // 0..127
  const int row0 = mtile * MT;

  const int tid = threadIdx.x;
  const int lane = tid & 63;
  const int wid = tid >> 6;   // 0..3
  const int l16 = lane & 15;
  const int quad = lane >> 4; // 0..3

  if (tid < MT) dinv_s[tid] = dinv[b * NROW + row0 + tid];

  const float* adj_b = adj + ((size_t)b * NROW + row0) * NROW;
  const __hip_bfloat16* xst_b = xst + (size_t)b * FDIM * NROW;

  // B fragment pointers: f = wid*32 + ct*16 + l16; k-offset = quad*8 (+32 for kk=1)
  const __hip_bfloat16* gb0 = xst_b + (size_t)(wid * 32 + l16) * NROW + quad * 8;
  const __hip_bfloat16* gb1 = gb0 + (size_t)16 * NROW;

  f32x4 zero4;
  zero4.x = 0.f; zero4.y = 0.f; zero4.z = 0.f; zero4.w = 0.f;
  f32x4 acc[2][2];
#pragma unroll
  for (int rt = 0; rt < 2; ++rt)
#pragma unroll
    for (int ct = 0; ct < 2; ++ct) acc[rt][ct] = zero4;

  // A staging indices
  const int ar = tid >> 3;          // A: row 0..31
  const int ac = (tid & 7) * 8;     // A: k-offset 0..56 (8 fp32 each)
  const float* ga = adj_b + (size_t)ar * NROW + ac;

  // prologue: A tile 0 into regs; B fragments for tile 0 into regs.
  float4 pa0 = *(const float4*)(ga);
  float4 pa1 = *(const float4*)(ga + 4);
  bf16x8 pbf00 = *(const bf16x8*)(gb0);        // kk=0, ct=0
  bf16x8 pbf01 = *(const bf16x8*)(gb1);        // kk=0, ct=1
  bf16x8 pbf10 = *(const bf16x8*)(gb0 + 32);   // kk=1, ct=0
  bf16x8 pbf11 = *(const bf16x8*)(gb1 + 32);   // kk=1, ct=1

  int p = 0;
  for (int k0 = 0; k0 < NROW; k0 += KC) {
    const int kn = k0 + KC;
    {  // drain A prefetch regs -> LDS buf[p]
      union { __hip_bfloat16 h[8]; uint4 u; } t;
      t.h[0] = __float2bfloat16(pa0.x); t.h[1] = __float2bfloat16(pa0.y);
      t.h[2] = __float2bfloat16(pa0.z); t.h[3] = __float2bfloat16(pa0.w);
      t.h[4] = __float2bfloat16(pa1.x); t.h[5] = __float2bfloat16(pa1.y);
      t.h[6] = __float2bfloat16(pa1.z); t.h[7] = __float2bfloat16(pa1.w);
      *(uint4*)&sm.As[p][ar * AS_ST + ac] = t.u;
    }
    if (kn < NROW) {  // issue next A tile loads; fly across barrier + MFMA
      const float* gan = ga + kn;
      pa0 = *(const float4*)(gan);
      pa1 = *(const float4*)(gan + 4);
    }
    __syncthreads();

    // ---- kk = 0: uses pbf00/pbf01 ----
    bf16x8 af00 = *(const bf16x8*)&sm.As[p][(l16) * AS_ST + quad * 8];
    bf16x8 af01 = *(const bf16x8*)&sm.As[p][(16 + l16) * AS_ST + quad * 8];
    acc[0][0] = __builtin_amdgcn_mfma_f32_16x16x32_bf16(af00, pbf00, acc[0][0], 0, 0, 0);
    acc[0][1] = __builtin_amdgcn_mfma_f32_16x16x32_bf16(af00, pbf01, acc[0][1], 0, 0, 0);
    acc[1][0] = __builtin_amdgcn_mfma_f32_16x16x32_bf16(af01, pbf00, acc[1][0], 0, 0, 0);
    acc[1][1] = __builtin_amdgcn_mfma_f32_16x16x32_bf16(af01, pbf01, acc[1][1], 0, 0, 0);
    if (kn < NROW) {  // reload kk=0 B frags for next tile (WAR after last use)
      pbf00 = *(const bf16x8*)(gb0 + kn);
      pbf01 = *(const bf16x8*)(gb1 + kn);
    }

    // ---- kk = 1: uses pbf10/pbf11 ----
    bf16x8 af10 = *(const bf16x8*)&sm.As[p][(l16) * AS_ST + 32 + quad * 8];
    bf16x8 af11 = *(const bf16x8*)&sm.As[p][(16 + l16) * AS_ST + 32 + quad * 8];
    acc[0][0] = __builtin_amdgcn_mfma_f32_16x16x32_bf16(af10, pbf10, acc[0][0], 0, 0, 0);
    acc[0][1] = __builtin_amdgcn_mfma_f32_16x16x32_bf16(af10, pbf11, acc[0][1], 0, 0, 0);
    acc[1][0] = __builtin_amdgcn_mfma_f32_16x16x32_bf16(af11, pbf10, acc[1][0], 0, 0, 0);
    acc[1][1] = __builtin_amdgcn_mfma_f32_16x16x32_bf16(af11, pbf11, acc[1][1], 0, 0, 0);
    if (kn < NROW) {
      pbf10 = *(const bf16x8*)(gb0 + kn + 32);
      pbf11 = *(const bf16x8*)(gb1 + kn + 32);
    }
    p ^= 1;
  }
  __syncthreads();  // all MFMA reads done before LDS reuse

  // ---- epilogue: Z (scaled by dinv[n]) -> LDS bf16 A-layout.
  // C/D layout of 16x16x32: col = lane&15, row = quad*4 + reg.
#pragma unroll
  for (int rt = 0; rt < 2; ++rt)
#pragma unroll
    for (int ct = 0; ct < 2; ++ct)
#pragma unroll
      for (int i = 0; i < 4; ++i) {
        int r = rt * 16 + quad * 4 + i;
        int c = wid * 32 + ct * 16 + l16;
        sm.Zs[r * ZS_ST + c] = __float2bfloat16(acc[rt][ct][i] * dinv_s[r]);
      }
  __syncthreads();

  // second GEMM: Z @ W via pre-transposed bf16 wt[o][f] (32 KB, L2-resident):
  // B-frag element j = W[f=kk*32+quad*8+j][o] = wt[o*128 + kk*32+quad*8+j].
  f32x4 acc2[2][2];
#pragma unroll
  for (int rt = 0; rt < 2; ++rt)
#pragma unroll
    for (int ct = 0; ct < 2; ++ct) acc2[rt][ct] = zero4;
#pragma unroll
  for (int kk = 0; kk < 4; ++kk) {
    bf16x8 za[2], wb[2];
#pragma unroll
    for (int rt = 0; rt < 2; ++rt)
      za[rt] = *(const bf16x8*)&sm.Zs[(rt * 16 + l16) * ZS_ST + kk * 32 + quad * 8];
#pragma unroll
    for (int ct = 0; ct < 2; ++ct) {
      const int o = wid * 32 + ct * 16 + l16;
      wb[ct] = *(const bf16x8*)&wt[(size_t)o * FDIM + kk * 32 + quad * 8];
    }
#pragma unroll
    for (int rt = 0; rt < 2; ++rt)
#pragma unroll
      for (int ct = 0; ct < 2; ++ct)
        acc2[rt][ct] = __builtin_amdgcn_mfma_f32_16x16x32_bf16(za[rt], wb[ct], acc2[rt][ct], 0, 0, 0);
  }

  float bv[2];
  bv[0] = bias[wid * 32 + l16];
  bv[1] = bias[wid * 32 + 16 + l16];
  float* ob = out + ((size_t)b * NROW + row0) * FDIM;
#pragma unroll
  for (int rt = 0; rt < 2; ++rt)
#pragma unroll
    for (int ct = 0; ct < 2; ++ct)
#pragma unroll
      for (int i = 0; i < 4; ++i) {
        int r = rt * 16 + quad * 4 + i;
        int o = wid * 32 + ct * 16 + l16;
        ob[(size_t)r * FDIM + o] = acc2[rt][ct][i] + bv[ct];
      }
}

extern "C" void kernel_launch(void* const* d_in, const int* in_sizes, int n_in,
                              void* d_out, int out_size, void* d_ws, size_t ws_size,
                              hipStream_t stream) {
  const float* x    = (const float*)d_in[0];   // [4,4096,128]
  const float* adj  = (const float*)d_in[1];   // [4,4096,4096]
  const float* w    = (const float*)d_in[2];   // [128,128]
  const float* bias = (const float*)d_in[3];   // [128]
  float* out = (float*)d_out;                  // [4,4096,128]

  float* dinv = (float*)d_ws;                                        // 64 KB
  __hip_bfloat16* xst =
      (__hip_bfloat16*)((char*)d_ws + (size_t)NBATCH * NROW * sizeof(float));  // 4 MiB
  __hip_bfloat16* wt =
      (__hip_bfloat16*)((char*)d_ws + (size_t)NBATCH * NROW * sizeof(float)
                        + (size_t)NBATCH * NROW * FDIM * sizeof(__hip_bfloat16)); // 32 KB

  k_degree<<<NBATCH * NROW / 4, 256, 0, stream>>>(adj, dinv);
  k_xst<<<513, 256, 0, stream>>>(x, dinv, xst, w, wt);
  k_gemm<<<512, 256, 0, stream>>>(adj, xst, dinv, wt, bias, out);
}

// Round 4
// 425.984 us; speedup vs baseline: 1.0415x; 1.0415x over previous
//
#include <hip/hip_runtime.h>
#include <hip/hip_bf16.h>
#include <stdint.h>

// GCN: out = D^-1/2 A D^-1/2 X W + b
// B=4, N=4096, F_IN=F_OUT=128, all fp32 I/O.
// v6: revert to v2 (measured-best) GEMM structure: A reg-prefetch + LDS dbuf
// single barrier/iter, B staged via LDS (coalesced). Keep only the isolated-
// safe delta from v4/v5: bf16 pre-transposed wt[o][f] for the epilogue
// B-fragment (8 vector loads instead of 64 strided scalar fp32 + cvt).
// Evidence from v3/v4/v5: GEMM is neither A-byte-bound (v3), load-latency-
// bound (v4), nor helped by removing B LDS staging (v5 -- scattered 16 B
// fragment loads cost ~16x L2 requests). v2 is ~5-10% above the two-pass
// structural floor (degree 43 us + GEMM ~50 us + xst 4 us).

#define NROW 4096
#define FDIM 128
#define NBATCH 4

typedef __bf16 bf16x8 __attribute__((ext_vector_type(8)));
typedef float f32x4 __attribute__((ext_vector_type(4)));

// ---------------- kernel 1: degree + d^{-1/2} ----------------
// one WAVE per row: 64 lanes x 16 float4 = 16 KB row, 16 loads in flight/lane,
// no LDS, no block barrier. grid = 4096 blocks x 4 waves.
__global__ __launch_bounds__(256) void k_degree(const float* __restrict__ adj,
                                                float* __restrict__ dinv) {
  const int row = blockIdx.x * 4 + (threadIdx.x >> 6);  // b*NROW+n
  const int lane = threadIdx.x & 63;
  const float4* arow = (const float4*)(adj + (size_t)row * NROW);
  float s = 0.f;
#pragma unroll
  for (int i = 0; i < 16; ++i) {
    float4 v = arow[lane + i * 64];
    s += (v.x + v.y) + (v.z + v.w);
  }
#pragma unroll
  for (int off = 32; off > 0; off >>= 1) s += __shfl_down(s, off, 64);
  if (lane == 0) dinv[row] = 1.0f / sqrtf(s + 1e-6f);
}

// ---------------- kernel 2: Xst[b][f][m] = bf16(dinv[b,m] * x[b][m][f]) ----
// blocks 0..511: xst transpose+scale. block 512: wt[o][f] = bf16(W[f][o]).
__global__ __launch_bounds__(256) void k_xst(const float* __restrict__ x,
                                             const float* __restrict__ dinv,
                                             __hip_bfloat16* __restrict__ xst,
                                             const float* __restrict__ w,
                                             __hip_bfloat16* __restrict__ wt) {
  const int bid = blockIdx.x;
  const int tid = threadIdx.x;

  if (bid == 512) {  // W transpose -> bf16 (32 KB, one block)
    const int o = tid >> 1;
    const int f0 = (tid & 1) * 64;
    union { __hip_bfloat16 h[64]; uint4 v[8]; } t;
#pragma unroll
    for (int j = 0; j < 64; ++j)
      t.h[j] = __float2bfloat16(w[(size_t)(f0 + j) * FDIM + o]);
    uint4* dst = (uint4*)(wt + (size_t)o * FDIM + f0);
#pragma unroll
    for (int j = 0; j < 8; ++j) dst[j] = t.v[j];
    return;
  }

  const int b = bid >> 7;            // 0..3
  const int m0 = (bid & 127) * 32;   // 0..4064
  __shared__ float tile[32 * 132];
  {
    const int ml = tid >> 3;          // 0..31
    const int fl = (tid & 7) * 16;    // 0..112
    const float dv = dinv[b * NROW + m0 + ml];
    const float* gx = x + ((size_t)b * NROW + m0 + ml) * FDIM + fl;
    float* dst = &tile[ml * 132 + fl];
#pragma unroll
    for (int j = 0; j < 16; j += 4) {
      float4 v = *(const float4*)(gx + j);
      v.x *= dv; v.y *= dv; v.z *= dv; v.w *= dv;
      *(float4*)(dst + j) = v;
    }
  }
  __syncthreads();
  {
    const int f = tid >> 1;           // 0..127
    const int mc = (tid & 1) * 16;    // 0 or 16
    union { __hip_bfloat16 h[16]; uint4 v[2]; } tmp;
#pragma unroll
    for (int j = 0; j < 16; ++j)
      tmp.h[j] = __float2bfloat16(tile[(mc + j) * 132 + f]);
    __hip_bfloat16* dst = xst + ((size_t)b * FDIM + f) * NROW + m0 + mc;
    *(uint4*)(dst) = tmp.v[0];
    *(uint4*)(dst + 8) = tmp.v[1];
  }
}

// ---------------- kernel 3: main GEMM + fused epilogue ----------------
// 32 rows x 128 cols of Z per block; Kc=64; 4 waves, each 32x32 (2x2 of
// 16x16x32 bf16 MFMA). Register-prefetch + LDS dbuf: prefetch loads for
// tile k+1 stay in flight across the single per-iter barrier + MFMA phase.
#define MT 32
#define KC 64
#define AS_ST 72    // 64+8 bf16
#define BS_ST 72
#define ZS_ST 136   // 128+8

__global__ __launch_bounds__(256, 2)
void k_gemm(const float* __restrict__ adj, const __hip_bfloat16* __restrict__ xst,
            const float* __restrict__ dinv, const __hip_bfloat16* __restrict__ wt,
            const float* __restrict__ bias, float* __restrict__ out) {
  __shared__ union {
    struct { __hip_bfloat16 As[2][MT * AS_ST]; __hip_bfloat16 Bs[2][FDIM * BS_ST]; } lp; // 46080 B
    __hip_bfloat16 Zs[MT * ZS_ST];                                                       // 8704 B
  } sm;
  __shared__ float dinv_s[MT];

  // XCD swizzle: same batch stays on an XCD pair -> Xst slice L2-resident.
  const int bid = blockIdx.x;            // 0..511
  const int xcd = bid & 7;
  const int b = xcd >> 1;                // 0..3
  const int mtile = (bid >> 3) * 2 + (xcd & 1);  // 0..127
  const int row0 = mtile * MT;

  const int tid = threadIdx.x;
  const int lane = tid & 63;
  const int wid = tid >> 6;   // 0..3
  const int l16 = lane & 15;
  const int quad = lane >> 4; // 0..3

  if (tid < MT) dinv_s[tid] = dinv[b * NROW + row0 + tid];

  const float* adj_b = adj + ((size_t)b * NROW + row0) * NROW;
  const __hip_bfloat16* xst_b = xst + (size_t)b * FDIM * NROW;

  f32x4 zero4;
  zero4.x = 0.f; zero4.y = 0.f; zero4.z = 0.f; zero4.w = 0.f;
  f32x4 acc[2][2];
#pragma unroll
  for (int rt = 0; rt < 2; ++rt)
#pragma unroll
    for (int ct = 0; ct < 2; ++ct) acc[rt][ct] = zero4;

  // staging indices
  const int ar = tid >> 3;          // A: row 0..31
  const int ac = (tid & 7) * 8;     // A: k-offset 0..56 (8 fp32 each)
  const int bfr = tid >> 1;         // B: f-row 0..127
  const int bcc = (tid & 1) * 32;   // B: k-offset 0 or 32 (32 bf16 each)
  const float* ga = adj_b + (size_t)ar * NROW + ac;
  const __hip_bfloat16* gb = xst_b + (size_t)bfr * NROW + bcc;

  // prologue: prefetch tile 0 into registers
  float4 pa0 = *(const float4*)(ga);
  float4 pa1 = *(const float4*)(ga + 4);
  uint4 pb0 = ((const uint4*)gb)[0];
  uint4 pb1 = ((const uint4*)gb)[1];
  uint4 pb2 = ((const uint4*)gb)[2];
  uint4 pb3 = ((const uint4*)gb)[3];

  int p = 0;
  for (int k0 = 0; k0 < NROW; k0 += KC) {
    {  // drain prefetch regs -> LDS buf[p]
      union { __hip_bfloat16 h[8]; uint4 u; } t;
      t.h[0] = __float2bfloat16(pa0.x); t.h[1] = __float2bfloat16(pa0.y);
      t.h[2] = __float2bfloat16(pa0.z); t.h[3] = __float2bfloat16(pa0.w);
      t.h[4] = __float2bfloat16(pa1.x); t.h[5] = __float2bfloat16(pa1.y);
      t.h[6] = __float2bfloat16(pa1.z); t.h[7] = __float2bfloat16(pa1.w);
      *(uint4*)&sm.lp.As[p][ar * AS_ST + ac] = t.u;
      __hip_bfloat16* q = &sm.lp.Bs[p][bfr * BS_ST + bcc];
      *(uint4*)(q) = pb0;
      *(uint4*)(q + 8) = pb1;
      *(uint4*)(q + 16) = pb2;
      *(uint4*)(q + 24) = pb3;
    }
    if (k0 + KC < NROW) {  // issue next-tile loads; they fly across barrier+MFMA
      const float* gan = ga + k0 + KC;
      pa0 = *(const float4*)(gan);
      pa1 = *(const float4*)(gan + 4);
      const __hip_bfloat16* gbn = gb + k0 + KC;
      pb0 = ((const uint4*)gbn)[0];
      pb1 = ((const uint4*)gbn)[1];
      pb2 = ((const uint4*)gbn)[2];
      pb3 = ((const uint4*)gbn)[3];
    }
    __syncthreads();   // single barrier per iter (dbuf makes 2nd unnecessary)
#pragma unroll
    for (int kk = 0; kk < 2; ++kk) {
      bf16x8 af[2], bfv[2];
#pragma unroll
      for (int rt = 0; rt < 2; ++rt)
        af[rt] = *(const bf16x8*)&sm.lp.As[p][(rt * 16 + l16) * AS_ST + kk * 32 + quad * 8];
#pragma unroll
      for (int ct = 0; ct < 2; ++ct)
        bfv[ct] = *(const bf16x8*)&sm.lp.Bs[p][(wid * 32 + ct * 16 + l16) * BS_ST + kk * 32 + quad * 8];
#pragma unroll
      for (int rt = 0; rt < 2; ++rt)
#pragma unroll
        for (int ct = 0; ct < 2; ++ct)
          acc[rt][ct] = __builtin_amdgcn_mfma_f32_16x16x32_bf16(af[rt], bfv[ct], acc[rt][ct], 0, 0, 0);
    }
    p ^= 1;
  }
  __syncthreads();  // all MFMA reads done before LDS reuse

  // ---- epilogue: Z (scaled by dinv[n]) -> LDS bf16 A-layout.
  // C/D layout of 16x16x32: col = lane&15, row = quad*4 + reg.
#pragma unroll
  for (int rt = 0; rt < 2; ++rt)
#pragma unroll
    for (int ct = 0; ct < 2; ++ct)
#pragma unroll
      for (int i = 0; i < 4; ++i) {
        int r = rt * 16 + quad * 4 + i;
        int c = wid * 32 + ct * 16 + l16;
        sm.Zs[r * ZS_ST + c] = __float2bfloat16(acc[rt][ct][i] * dinv_s[r]);
      }
  __syncthreads();

  // second GEMM: Z @ W via pre-transposed bf16 wt[o][f] (32 KB, L2-resident):
  // B-frag element j = W[f=kk*32+quad*8+j][o] = wt[o*128 + kk*32+quad*8+j].
  f32x4 acc2[2][2];
#pragma unroll
  for (int rt = 0; rt < 2; ++rt)
#pragma unroll
    for (int ct = 0; ct < 2; ++ct) acc2[rt][ct] = zero4;
#pragma unroll
  for (int kk = 0; kk < 4; ++kk) {
    bf16x8 za[2], wb[2];
#pragma unroll
    for (int rt = 0; rt < 2; ++rt)
      za[rt] = *(const bf16x8*)&sm.Zs[(rt * 16 + l16) * ZS_ST + kk * 32 + quad * 8];
#pragma unroll
    for (int ct = 0; ct < 2; ++ct) {
      const int o = wid * 32 + ct * 16 + l16;
      wb[ct] = *(const bf16x8*)&wt[(size_t)o * FDIM + kk * 32 + quad * 8];
    }
#pragma unroll
    for (int rt = 0; rt < 2; ++rt)
#pragma unroll
      for (int ct = 0; ct < 2; ++ct)
        acc2[rt][ct] = __builtin_amdgcn_mfma_f32_16x16x32_bf16(za[rt], wb[ct], acc2[rt][ct], 0, 0, 0);
  }

  float bv[2];
  bv[0] = bias[wid * 32 + l16];
  bv[1] = bias[wid * 32 + 16 + l16];
  float* ob = out + ((size_t)b * NROW + row0) * FDIM;
#pragma unroll
  for (int rt = 0; rt < 2; ++rt)
#pragma unroll
    for (int ct = 0; ct < 2; ++ct)
#pragma unroll
      for (int i = 0; i < 4; ++i) {
        int r = rt * 16 + quad * 4 + i;
        int o = wid * 32 + ct * 16 + l16;
        ob[(size_t)r * FDIM + o] = acc2[rt][ct][i] + bv[ct];
      }
}

extern "C" void kernel_launch(void* const* d_in, const int* in_sizes, int n_in,
                              void* d_out, int out_size, void* d_ws, size_t ws_size,
                              hipStream_t stream) {
  const float* x    = (const float*)d_in[0];   // [4,4096,128]
  const float* adj  = (const float*)d_in[1];   // [4,4096,4096]
  const float* w    = (const float*)d_in[2];   // [128,128]
  const float* bias = (const float*)d_in[3];   // [128]
  float* out = (float*)d_out;                  // [4,4096,128]

  float* dinv = (float*)d_ws;                                        // 64 KB
  __hip_bfloat16* xst =
      (__hip_bfloat16*)((char*)d_ws + (size_t)NBATCH * NROW * sizeof(float));  // 4 MiB
  __hip_bfloat16* wt =
      (__hip_bfloat16*)((char*)d_ws + (size_t)NBATCH * NROW * sizeof(float)
                        + (size_t)NBATCH * NROW * FDIM * sizeof(__hip_bfloat16)); // 32 KB

  k_degree<<<NBATCH * NROW / 4, 256, 0, stream>>>(adj, dinv);
  k_xst<<<513, 256, 0, stream>>>(x, dinv, xst, w, wt);
  k_gemm<<<512, 256, 0, stream>>>(adj, xst, dinv, wt, bias, out);
}

// Round 6
// 422.211 us; speedup vs baseline: 1.0508x; 1.0089x over previous
//
#include <hip/hip_runtime.h>
#include <hip/hip_bf16.h>
#include <stdint.h>

// GCN: out = D^-1/2 A D^-1/2 X W + b
// B=4, N=4096, F_IN=F_OUT=128, all fp32 I/O.
// v8 == v2 (best measured, 419.8 us) + one safety change: SECOND
// __syncthreads() at the end of each K-iteration (canonical two-barrier
// double-buffer). Round-5 run of byte-identical v2 failed the post-timing
// tripwire intermittently (absmax 4.2e-2 after graph replays, correct
// during pytest) -- signature of a rare scheduling-dependent race. The
// single-barrier dbuf was the only structure whose safety rested on
// compiler scheduling discipline rather than explicit sync; the extra
// barrier costs ~1-2 us (vmcnt/lgkmcnt already drain at the first
// barrier) and makes the loop provably race-free.
// Session ledger: dur = ~320 us fixed harness poison-fills (2x 1 GiB @
// ~160 us, untouchable) + ~99 us variable. Variable floor = two mandatory
// adj passes (degree 43 + GEMM ~50 + xst ~5) ~= 95 us. Structural
// alternatives all measured neutral-to-negative:
//   v3 adjh bf16 copy (+128 MiB write, GEMM not A-byte-bound): +30 us
//   v4 2-deep reg prefetch (not load-latency-bound): +10 us
//   v5 B direct from L2 (scattered 16 B frags, ~16x L2 reqs): +25 us
//   v6 bf16 wt epilogue (epilogue not on critical path): +7 us

#define NROW 4096
#define FDIM 128
#define NBATCH 4

typedef __bf16 bf16x8 __attribute__((ext_vector_type(8)));
typedef float f32x4 __attribute__((ext_vector_type(4)));

// ---------------- kernel 1: degree + d^{-1/2} ----------------
// one WAVE per row: 64 lanes x 16 float4 = 16 KB row, 16 loads in flight/lane,
// no LDS, no block barrier. grid = 4096 blocks x 4 waves.
__global__ __launch_bounds__(256) void k_degree(const float* __restrict__ adj,
                                                float* __restrict__ dinv) {
  const int row = blockIdx.x * 4 + (threadIdx.x >> 6);  // b*NROW+n
  const int lane = threadIdx.x & 63;
  const float4* arow = (const float4*)(adj + (size_t)row * NROW);
  float s = 0.f;
#pragma unroll
  for (int i = 0; i < 16; ++i) {
    float4 v = arow[lane + i * 64];
    s += (v.x + v.y) + (v.z + v.w);
  }
#pragma unroll
  for (int off = 32; off > 0; off >>= 1) s += __shfl_down(s, off, 64);
  if (lane == 0) dinv[row] = 1.0f / sqrtf(s + 1e-6f);
}

// ---------------- kernel 2: Xst[b][f][m] = bf16(dinv[b,m] * x[b][m][f]) ----
__global__ __launch_bounds__(256) void k_xst(const float* __restrict__ x,
                                             const float* __restrict__ dinv,
                                             __hip_bfloat16* __restrict__ xst) {
  const int bid = blockIdx.x;        // 512 blocks
  const int b = bid >> 7;            // 0..3
  const int m0 = (bid & 127) * 32;   // 0..4064
  const int tid = threadIdx.x;
  __shared__ float tile[32 * 132];

  {
    const int ml = tid >> 3;          // 0..31
    const int fl = (tid & 7) * 16;    // 0..112
    const float dv = dinv[b * NROW + m0 + ml];
    const float* gx = x + ((size_t)b * NROW + m0 + ml) * FDIM + fl;
    float* dst = &tile[ml * 132 + fl];
#pragma unroll
    for (int j = 0; j < 16; j += 4) {
      float4 v = *(const float4*)(gx + j);
      v.x *= dv; v.y *= dv; v.z *= dv; v.w *= dv;
      *(float4*)(dst + j) = v;
    }
  }
  __syncthreads();
  {
    const int f = tid >> 1;           // 0..127
    const int mc = (tid & 1) * 16;    // 0 or 16
    union { __hip_bfloat16 h[16]; uint4 v[2]; } tmp;
#pragma unroll
    for (int j = 0; j < 16; ++j)
      tmp.h[j] = __float2bfloat16(tile[(mc + j) * 132 + f]);
    __hip_bfloat16* dst = xst + ((size_t)b * FDIM + f) * NROW + m0 + mc;
    *(uint4*)(dst) = tmp.v[0];
    *(uint4*)(dst + 8) = tmp.v[1];
  }
}

// ---------------- kernel 3: main GEMM + fused epilogue ----------------
// 32 rows x 128 cols of Z per block; Kc=64; 4 waves, each 32x32 (2x2 of
// 16x16x32 bf16 MFMA). Register-prefetch + LDS dbuf, TWO barriers per
// K-iter (write-sync + read-sync) -- provably race-free.
#define MT 32
#define KC 64
#define AS_ST 72    // 64+8 bf16
#define BS_ST 72
#define ZS_ST 136   // 128+8

__global__ __launch_bounds__(256, 2)
void k_gemm(const float* __restrict__ adj, const __hip_bfloat16* __restrict__ xst,
            const float* __restrict__ dinv, const float* __restrict__ w,
            const float* __restrict__ bias, float* __restrict__ out) {
  __shared__ union {
    struct { __hip_bfloat16 As[2][MT * AS_ST]; __hip_bfloat16 Bs[2][FDIM * BS_ST]; } lp; // 46080 B
    __hip_bfloat16 Zs[MT * ZS_ST];                                                       // 8704 B
  } sm;
  __shared__ float dinv_s[MT];

  // XCD swizzle: same batch stays on an XCD pair -> Xst slice L2-resident.
  const int bid = blockIdx.x;            // 0..511
  const int xcd = bid & 7;
  const int b = xcd >> 1;                // 0..3
  const int mtile = (bid >> 3) * 2 + (xcd & 1);  // 0..127
  const int row0 = mtile * MT;

  const int tid = threadIdx.x;
  const int lane = tid & 63;
  const int wid = tid >> 6;   // 0..3
  const int l16 = lane & 15;
  const int quad = lane >> 4; // 0..3

  if (tid < MT) dinv_s[tid] = dinv[b * NROW + row0 + tid];

  const float* adj_b = adj + ((size_t)b * NROW + row0) * NROW;
  const __hip_bfloat16* xst_b = xst + (size_t)b * FDIM * NROW;

  f32x4 zero4;
  zero4.x = 0.f; zero4.y = 0.f; zero4.z = 0.f; zero4.w = 0.f;
  f32x4 acc[2][2];
#pragma unroll
  for (int rt = 0; rt < 2; ++rt)
#pragma unroll
    for (int ct = 0; ct < 2; ++ct) acc[rt][ct] = zero4;

  // staging indices
  const int ar = tid >> 3;          // A: row 0..31
  const int ac = (tid & 7) * 8;     // A: k-offset 0..56 (8 fp32 each)
  const int bfr = tid >> 1;         // B: f-row 0..127
  const int bcc = (tid & 1) * 32;   // B: k-offset 0 or 32 (32 bf16 each)
  const float* ga = adj_b + (size_t)ar * NROW + ac;
  const __hip_bfloat16* gb = xst_b + (size_t)bfr * NROW + bcc;

  // prologue: prefetch tile 0 into registers
  float4 pa0 = *(const float4*)(ga);
  float4 pa1 = *(const float4*)(ga + 4);
  uint4 pb0 = ((const uint4*)gb)[0];
  uint4 pb1 = ((const uint4*)gb)[1];
  uint4 pb2 = ((const uint4*)gb)[2];
  uint4 pb3 = ((const uint4*)gb)[3];

  int p = 0;
  for (int k0 = 0; k0 < NROW; k0 += KC) {
    {  // drain prefetch regs -> LDS buf[p]
      union { __hip_bfloat16 h[8]; uint4 u; } t;
      t.h[0] = __float2bfloat16(pa0.x); t.h[1] = __float2bfloat16(pa0.y);
      t.h[2] = __float2bfloat16(pa0.z); t.h[3] = __float2bfloat16(pa0.w);
      t.h[4] = __float2bfloat16(pa1.x); t.h[5] = __float2bfloat16(pa1.y);
      t.h[6] = __float2bfloat16(pa1.z); t.h[7] = __float2bfloat16(pa1.w);
      *(uint4*)&sm.lp.As[p][ar * AS_ST + ac] = t.u;
      __hip_bfloat16* q = &sm.lp.Bs[p][bfr * BS_ST + bcc];
      *(uint4*)(q) = pb0;
      *(uint4*)(q + 8) = pb1;
      *(uint4*)(q + 16) = pb2;
      *(uint4*)(q + 24) = pb3;
    }
    if (k0 + KC < NROW) {  // issue next-tile loads
      const float* gan = ga + k0 + KC;
      pa0 = *(const float4*)(gan);
      pa1 = *(const float4*)(gan + 4);
      const __hip_bfloat16* gbn = gb + k0 + KC;
      pb0 = ((const uint4*)gbn)[0];
      pb1 = ((const uint4*)gbn)[1];
      pb2 = ((const uint4*)gbn)[2];
      pb3 = ((const uint4*)gbn)[3];
    }
    __syncthreads();   // writes to buf[p] visible to all waves
#pragma unroll
    for (int kk = 0; kk < 2; ++kk) {
      bf16x8 af[2], bfv[2];
#pragma unroll
      for (int rt = 0; rt < 2; ++rt)
        af[rt] = *(const bf16x8*)&sm.lp.As[p][(rt * 16 + l16) * AS_ST + kk * 32 + quad * 8];
#pragma unroll
      for (int ct = 0; ct < 2; ++ct)
        bfv[ct] = *(const bf16x8*)&sm.lp.Bs[p][(wid * 32 + ct * 16 + l16) * BS_ST + kk * 32 + quad * 8];
#pragma unroll
      for (int rt = 0; rt < 2; ++rt)
#pragma unroll
        for (int ct = 0; ct < 2; ++ct)
          acc[rt][ct] = __builtin_amdgcn_mfma_f32_16x16x32_bf16(af[rt], bfv[ct], acc[rt][ct], 0, 0, 0);
    }
    __syncthreads();   // all reads of buf[p] done before it is rewritten
    p ^= 1;
  }

  // ---- epilogue: Z (scaled by dinv[n]) -> LDS bf16 A-layout.
  // C/D layout of 16x16x32: col = lane&15, row = quad*4 + reg.
#pragma unroll
  for (int rt = 0; rt < 2; ++rt)
#pragma unroll
    for (int ct = 0; ct < 2; ++ct)
#pragma unroll
      for (int i = 0; i < 4; ++i) {
        int r = rt * 16 + quad * 4 + i;
        int c = wid * 32 + ct * 16 + l16;
        sm.Zs[r * ZS_ST + c] = __float2bfloat16(acc[rt][ct][i] * dinv_s[r]);
      }
  __syncthreads();

  // second GEMM: Z @ W. W fragments straight from global (64 KB, L2-resident):
  // B-frag element = W[f = kk*32+quad*8+j][o = wid*32+ct*16+l16], lanes
  // consecutive in o -> coalesced 64 B per 16 lanes.
  f32x4 acc2[2][2];
#pragma unroll
  for (int rt = 0; rt < 2; ++rt)
#pragma unroll
    for (int ct = 0; ct < 2; ++ct) acc2[rt][ct] = zero4;
#pragma unroll
  for (int kk = 0; kk < 4; ++kk) {
    bf16x8 za[2], wb[2];
#pragma unroll
    for (int rt = 0; rt < 2; ++rt)
      za[rt] = *(const bf16x8*)&sm.Zs[(rt * 16 + l16) * ZS_ST + kk * 32 + quad * 8];
#pragma unroll
    for (int ct = 0; ct < 2; ++ct) {
      const int o = wid * 32 + ct * 16 + l16;
      const float* gw = w + (kk * 32 + quad * 8) * FDIM + o;
      union { __hip_bfloat16 h[8]; bf16x8 v; } tw;
#pragma unroll
      for (int j = 0; j < 8; ++j)
        tw.h[j] = __float2bfloat16(gw[j * FDIM]);
      wb[ct] = tw.v;
    }
#pragma unroll
    for (int rt = 0; rt < 2; ++rt)
#pragma unroll
      for (int ct = 0; ct < 2; ++ct)
        acc2[rt][ct] = __builtin_amdgcn_mfma_f32_16x16x32_bf16(za[rt], wb[ct], acc2[rt][ct], 0, 0, 0);
  }

  float bv[2];
  bv[0] = bias[wid * 32 + l16];
  bv[1] = bias[wid * 32 + 16 + l16];
  float* ob = out + ((size_t)b * NROW + row0) * FDIM;
#pragma unroll
  for (int rt = 0; rt < 2; ++rt)
#pragma unroll
    for (int ct = 0; ct < 2; ++ct)
#pragma unroll
      for (int i = 0; i < 4; ++i) {
        int r = rt * 16 + quad * 4 + i;
        int o = wid * 32 + ct * 16 + l16;
        ob[(size_t)r * FDIM + o] = acc2[rt][ct][i] + bv[ct];
      }
}

extern "C" void kernel_launch(void* const* d_in, const int* in_sizes, int n_in,
                              void* d_out, int out_size, void* d_ws, size_t ws_size,
                              hipStream_t stream) {
  const float* x    = (const float*)d_in[0];   // [4,4096,128]
  const float* adj  = (const float*)d_in[1];   // [4,4096,4096]
  const float* w    = (const float*)d_in[2];   // [128,128]
  const float* bias = (const float*)d_in[3];   // [128]
  float* out = (float*)d_out;                  // [4,4096,128]

  float* dinv = (float*)d_ws;                                        // 64 KB
  __hip_bfloat16* xst =
      (__hip_bfloat16*)((char*)d_ws + (size_t)NBATCH * NROW * sizeof(float));  // 4 MiB

  k_degree<<<NBATCH * NROW / 4, 256, 0, stream>>>(adj, dinv);
  k_xst<<<512, 256, 0, stream>>>(x, dinv, xst);
  k_gemm<<<512, 256, 0, stream>>>(adj, xst, dinv, w, bias, out);
}